// Round 1
// baseline (651.209 us; speedup 1.0000x reference)
//
#include <hip/hip_runtime.h>
#include <hip/hip_bf16.h>

typedef float v4f __attribute__((ext_vector_type(4)));

// ---------------- K0: wd_sum[k] = sum_o Wd_attn[k][o] ----------------
__global__ __launch_bounds__(256) void k_wdsum(const float* __restrict__ Wda,
                                               float* __restrict__ wd_sum) {
    int k = blockIdx.x, t = threadIdx.x;
    float s = Wda[k * 768 + t] + Wda[k * 768 + 256 + t] + Wda[k * 768 + 512 + t];
#pragma unroll
    for (int off = 32; off; off >>= 1) s += __shfl_down(s, off, 64);
    __shared__ float red[4];
    if ((t & 63) == 0) red[t >> 6] = s;
    __syncthreads();
    if (t == 0) wd_sum[k] = red[0] + red[1] + red[2] + red[3];
}

// ---------------- K1: t_attn[bi][o] = text@Wt + pos@Wp_attn + b_attn ----------------
// M=1024 rows (b,i), K=832 (768 text + 64 pos), N=768. Tile 64x64, grid (16,12).
__global__ __launch_bounds__(256) void k_tattn(const float* __restrict__ text,
                                               const float* __restrict__ pos,
                                               const float* __restrict__ Wt,
                                               const float* __restrict__ Wpa,
                                               const float* __restrict__ b_attn,
                                               float* __restrict__ t_attn) {
    __shared__ float At[64][68];  // [k][row], transposed so inner read is ds_read_b128
    __shared__ float Bt[64][64];  // [k][o]
    int t = threadIdx.x;
    int M0 = blockIdx.x * 64, N0 = blockIdx.y * 64;
    int r0 = (t >> 4) * 4, o0 = (t & 15) * 4;
    float acc[16] = {};
    for (int kc = 0; kc < 13; ++kc) {
        __syncthreads();
        for (int f = t * 4; f < 4096; f += 1024) {
            int row = f >> 6, kcol = f & 63;
            float4 v;
            if (kc < 12) v = *(const float4*)&text[(size_t)(M0 + row) * 768 + kc * 64 + kcol];
            else         v = *(const float4*)&pos[(size_t)(M0 + row) * 64 + kcol];
            At[kcol + 0][row] = v.x; At[kcol + 1][row] = v.y;
            At[kcol + 2][row] = v.z; At[kcol + 3][row] = v.w;
        }
        for (int f = t * 4; f < 4096; f += 1024) {
            int kr = f >> 6, oc = f & 63;
            float4 v;
            if (kc < 12) v = *(const float4*)&Wt[(size_t)(kc * 64 + kr) * 768 + N0 + oc];
            else         v = *(const float4*)&Wpa[(size_t)kr * 768 + N0 + oc];
            *(float4*)&Bt[kr][oc] = v;
        }
        __syncthreads();
#pragma unroll 8
        for (int k = 0; k < 64; ++k) {
            float4 a = *(const float4*)&At[k][r0];
            float4 b = *(const float4*)&Bt[k][o0];
            float av[4] = {a.x, a.y, a.z, a.w};
            float bv[4] = {b.x, b.y, b.z, b.w};
#pragma unroll
            for (int i = 0; i < 4; ++i)
#pragma unroll
                for (int j = 0; j < 4; ++j) acc[i * 4 + j] += av[i] * bv[j];
        }
    }
    float4 bias = *(const float4*)&b_attn[N0 + o0];
    float bb[4] = {bias.x, bias.y, bias.z, bias.w};
#pragma unroll
    for (int i = 0; i < 4; ++i) {
        float4 o;
        o.x = acc[i * 4 + 0] + bb[0]; o.y = acc[i * 4 + 1] + bb[1];
        o.z = acc[i * 4 + 2] + bb[2]; o.w = acc[i * 4 + 3] + bb[3];
        *(float4*)&t_attn[(size_t)(M0 + r0 + i) * 768 + N0 + o0] = o;
    }
}

// ---------------- K2 (mega): per (b,i): scores -> softmax -> p, pd, and r GEMM ----------------
// dep tile [128][64] staged transposed into LDS dt[k][j]; read once from HBM.
__global__ __launch_bounds__(256) void k_mega(const float* __restrict__ dep,
                                              const int* __restrict__ adj,
                                              const float* __restrict__ Wda,
                                              const float* __restrict__ t_attn,
                                              const float* __restrict__ wd_sum,
                                              float* __restrict__ r_out,
                                              float* __restrict__ out_p,
                                              float* __restrict__ pd_out) {
    __shared__ float dt[64][132];  // [k][j], +4 pad -> b128-aligned, conflict-free GEMM reads
    __shared__ float wb[64][64];   // Wd_attn o-chunk
    __shared__ float wds[64];
    __shared__ float sc[128];
    __shared__ float pv[128];
    __shared__ float pdp[4][64];
    __shared__ float red[8];
    int t = threadIdx.x;
    int bi = blockIdx.x;
    const float* depb = dep + (size_t)bi * (128 * 64);
    for (int f = t * 4; f < 8192; f += 1024) {
        int j = f >> 6, k0 = f & 63;
        float4 v = *(const float4*)&depb[f];
        dt[k0 + 0][j] = v.x; dt[k0 + 1][j] = v.y;
        dt[k0 + 2][j] = v.z; dt[k0 + 3][j] = v.w;
    }
    if (t < 64) wds[t] = wd_sum[t];
    const float* ta = t_attn + (size_t)bi * 768;
    // S_t = sum_o t_attn row (768 = 256 threads x 3)
    float s = ta[t] + ta[t + 256] + ta[t + 512];
#pragma unroll
    for (int off = 32; off; off >>= 1) s += __shfl_down(s, off, 64);
    if ((t & 63) == 0) red[t >> 6] = s;
    __syncthreads();
    float S_t = red[0] + red[1] + red[2] + red[3];
    // scores
    if (t < 128) {
        float d = 0.f;
#pragma unroll
        for (int k = 0; k < 64; ++k) d += dt[k][t] * wds[k];
        float v = S_t + d;
        if (adj[(size_t)bi * 128 + t] == 0) v += -1e30f;
        sc[t] = v;
    }
    __syncthreads();
    if (t < 64) {
        float v = fmaxf(sc[t], sc[t + 64]);
#pragma unroll
        for (int off = 32; off; off >>= 1) v = fmaxf(v, __shfl_down(v, off, 64));
        if (t == 0) red[4] = v;
    }
    __syncthreads();
    if (t < 128) pv[t] = __expf(sc[t] - red[4]);
    __syncthreads();
    if (t < 64) {
        float v = pv[t] + pv[t + 64];
#pragma unroll
        for (int off = 32; off; off >>= 1) v += __shfl_down(v, off, 64);
        if (t == 0) red[5] = v;
    }
    __syncthreads();
    float inv = 1.0f / red[5];
    if (t < 128) {
        float pj = pv[t] * inv;
        pv[t] = pj;
        out_p[(size_t)bi * 128 + t] = pj;
    }
    __syncthreads();
    // pd[k] = sum_j p[j] * dep[j][k]   (split j over 4 wave-segments)
    {
        int k = t & 63, seg = t >> 6;
        float a = 0.f;
#pragma unroll
        for (int jj = 0; jj < 32; ++jj) a += pv[seg * 32 + jj] * dt[k][seg * 32 + jj];
        pdp[seg][k] = a;
    }
    __syncthreads();
    if (t < 64) pd_out[(size_t)bi * 64 + t] = pdp[0][t] + pdp[1][t] + pdp[2][t] + pdp[3][t];

    // r GEMM: [128 j] x [768 o], K=64; micro-tile 4j x 8o per thread, 12 o-chunks of 64
    int j0 = (t >> 3) * 4;
    int o0 = (t & 7) * 8;
    float* rb = r_out + (size_t)bi * (128 * 768);
    for (int oc = 0; oc < 12; ++oc) {
        __syncthreads();
        for (int f = t * 4; f < 4096; f += 1024) {
            int k = f >> 6, o = f & 63;
            *(float4*)&wb[k][o] = *(const float4*)&Wda[(size_t)k * 768 + oc * 64 + o];
        }
        __syncthreads();
        float acc[32] = {};
#pragma unroll 4
        for (int k = 0; k < 64; ++k) {
            float4 a  = *(const float4*)&dt[k][j0];
            float4 b0 = *(const float4*)&wb[k][o0];
            float4 b1 = *(const float4*)&wb[k][o0 + 4];
            float av[4] = {a.x, a.y, a.z, a.w};
            float bv[8] = {b0.x, b0.y, b0.z, b0.w, b1.x, b1.y, b1.z, b1.w};
#pragma unroll
            for (int jj = 0; jj < 4; ++jj)
#pragma unroll
                for (int oo = 0; oo < 8; ++oo) acc[jj * 8 + oo] += av[jj] * bv[oo];
        }
        float4 t0 = *(const float4*)&ta[oc * 64 + o0];
        float4 t1 = *(const float4*)&ta[oc * 64 + o0 + 4];
        float tv[8] = {t0.x, t0.y, t0.z, t0.w, t1.x, t1.y, t1.z, t1.w};
#pragma unroll
        for (int jj = 0; jj < 4; ++jj) {
            float* dst = &rb[(size_t)(j0 + jj) * 768 + oc * 64 + o0];
            v4f w0 = {acc[jj * 8 + 0] + tv[0], acc[jj * 8 + 1] + tv[1],
                      acc[jj * 8 + 2] + tv[2], acc[jj * 8 + 3] + tv[3]};
            v4f w1 = {acc[jj * 8 + 4] + tv[4], acc[jj * 8 + 5] + tv[5],
                      acc[jj * 8 + 6] + tv[6], acc[jj * 8 + 7] + tv[7]};
            __builtin_nontemporal_store(w0, (v4f*)dst);
            __builtin_nontemporal_store(w1, (v4f*)(dst + 4));
        }
    }
}

// ---------------- K3: output_sum = text + pos@Wp + bp + bd + pd@Wd ----------------
// 8 (b,i) rows per block to amortize Wp/Wd reads through L2.
__global__ __launch_bounds__(256) void k_out(const float* __restrict__ text,
                                             const float* __restrict__ pos,
                                             const float* __restrict__ Wp,
                                             const float* __restrict__ bp,
                                             const float* __restrict__ Wd,
                                             const float* __restrict__ bd,
                                             const float* __restrict__ pd,
                                             float* __restrict__ outp) {
    __shared__ float ps[8][64];
    __shared__ float pdl[8][64];
    int t = threadIdx.x;
    int bi0 = blockIdx.x * 8;
    for (int f = t; f < 512; f += 256) {
        int g = f >> 6, k = f & 63;
        ps[g][k]  = pos[(size_t)(bi0 + g) * 64 + k];
        pdl[g][k] = pd[(size_t)(bi0 + g) * 64 + k];
    }
    __syncthreads();
    if (t < 192) {
        int d0 = t * 4;
        float acc[32] = {};
#pragma unroll 4
        for (int k = 0; k < 64; ++k) {
            float4 wp = *(const float4*)&Wp[(size_t)k * 768 + d0];
            float4 wd = *(const float4*)&Wd[(size_t)k * 768 + d0];
            float wpv[4] = {wp.x, wp.y, wp.z, wp.w};
            float wdv[4] = {wd.x, wd.y, wd.z, wd.w};
#pragma unroll
            for (int g = 0; g < 8; ++g) {
                float pk = ps[g][k], dk = pdl[g][k];
#pragma unroll
                for (int c = 0; c < 4; ++c) acc[g * 4 + c] += pk * wpv[c] + dk * wdv[c];
            }
        }
        float4 bpv = *(const float4*)&bp[d0];
        float4 bdv = *(const float4*)&bd[d0];
        float bb[4] = {bpv.x + bdv.x, bpv.y + bdv.y, bpv.z + bdv.z, bpv.w + bdv.w};
#pragma unroll
        for (int g = 0; g < 8; ++g) {
            float4 tx = *(const float4*)&text[(size_t)(bi0 + g) * 768 + d0];
            float4 o;
            o.x = acc[g * 4 + 0] + tx.x + bb[0];
            o.y = acc[g * 4 + 1] + tx.y + bb[1];
            o.z = acc[g * 4 + 2] + tx.z + bb[2];
            o.w = acc[g * 4 + 3] + tx.w + bb[3];
            *(float4*)&outp[(size_t)(bi0 + g) * 768 + d0] = o;
        }
    }
}

extern "C" void kernel_launch(void* const* d_in, const int* in_sizes, int n_in,
                              void* d_out, int out_size, void* d_ws, size_t ws_size,
                              hipStream_t stream) {
    const float* text   = (const float*)d_in[0];
    const int*   adj    = (const int*)d_in[1];
    const float* dep    = (const float*)d_in[2];
    const float* pos    = (const float*)d_in[3];
    const float* Wt     = (const float*)d_in[4];
    const float* Wpa    = (const float*)d_in[5];
    const float* Wda    = (const float*)d_in[6];
    const float* b_attn = (const float*)d_in[7];
    const float* Wd     = (const float*)d_in[8];
    const float* bd     = (const float*)d_in[9];
    const float* Wp     = (const float*)d_in[10];
    const float* bp     = (const float*)d_in[11];

    float* out    = (float*)d_out;
    float* r_out  = out;                                   // [8,128,128,768]
    float* os_out = out + (size_t)8 * 128 * 128 * 768;     // [8,128,768]
    float* p_out  = os_out + (size_t)8 * 128 * 768;        // [8,128,128]

    float* ws     = (float*)d_ws;
    float* t_attn = ws;            // 1024*768
    float* wd_sum = ws + 786432;   // 64
    float* pd     = ws + 786496;   // 1024*64

    k_wdsum<<<64, 256, 0, stream>>>(Wda, wd_sum);
    k_tattn<<<dim3(16, 12), 256, 0, stream>>>(text, pos, Wt, Wpa, b_attn, t_attn);
    k_mega<<<1024, 256, 0, stream>>>(dep, adj, Wda, t_attn, wd_sum, r_out, p_out, pd);
    k_out<<<128, 256, 0, stream>>>(text, pos, Wp, bp, Wd, bd, pd, os_out);
}

// Round 2
// 620.962 us; speedup vs baseline: 1.0487x; 1.0487x over previous
//
#include <hip/hip_runtime.h>
#include <hip/hip_bf16.h>

typedef float v4f __attribute__((ext_vector_type(4)));
typedef short short8 __attribute__((ext_vector_type(8)));

__device__ inline ushort f2bf(float x) {
    unsigned u = __float_as_uint(x);
    unsigned r = u + 0x7fffu + ((u >> 16) & 1u);
    return (ushort)(r >> 16);
}

// ---------------- K0: wd_sum[k] = sum_o Wd_attn[k][o] ----------------
__global__ __launch_bounds__(256) void k_wdsum(const float* __restrict__ Wda,
                                               float* __restrict__ wd_sum) {
    int k = blockIdx.x, t = threadIdx.x;
    float s = Wda[k * 768 + t] + Wda[k * 768 + 256 + t] + Wda[k * 768 + 512 + t];
#pragma unroll
    for (int off = 32; off; off >>= 1) s += __shfl_down(s, off, 64);
    __shared__ float red[4];
    if ((t & 63) == 0) red[t >> 6] = s;
    __syncthreads();
    if (t == 0) wd_sum[k] = red[0] + red[1] + red[2] + red[3];
}

// ---------------- K0b: WdaT_bf16[o][k] = bf16(Wda[k][o]) ----------------
__global__ __launch_bounds__(256) void k_cvt(const float* __restrict__ Wda,
                                             ushort* __restrict__ wdat) {
    int idx = blockIdx.x * 256 + threadIdx.x;  // 49152 total
    int o = idx >> 6, k = idx & 63;
    wdat[idx] = f2bf(Wda[(size_t)k * 768 + o]);
}

// ---------------- K1: t_attn[bi][o] = text@Wt + pos@Wp_attn + b_attn ----------------
__global__ __launch_bounds__(256) void k_tattn(const float* __restrict__ text,
                                               const float* __restrict__ pos,
                                               const float* __restrict__ Wt,
                                               const float* __restrict__ Wpa,
                                               const float* __restrict__ b_attn,
                                               float* __restrict__ t_attn) {
    __shared__ float At[64][68];
    __shared__ float Bt[64][64];
    int t = threadIdx.x;
    int M0 = blockIdx.x * 64, N0 = blockIdx.y * 64;
    int r0 = (t >> 4) * 4, o0 = (t & 15) * 4;
    float acc[16] = {};
    for (int kc = 0; kc < 13; ++kc) {
        __syncthreads();
        for (int f = t * 4; f < 4096; f += 1024) {
            int row = f >> 6, kcol = f & 63;
            float4 v;
            if (kc < 12) v = *(const float4*)&text[(size_t)(M0 + row) * 768 + kc * 64 + kcol];
            else         v = *(const float4*)&pos[(size_t)(M0 + row) * 64 + kcol];
            At[kcol + 0][row] = v.x; At[kcol + 1][row] = v.y;
            At[kcol + 2][row] = v.z; At[kcol + 3][row] = v.w;
        }
        for (int f = t * 4; f < 4096; f += 1024) {
            int kr = f >> 6, oc = f & 63;
            float4 v;
            if (kc < 12) v = *(const float4*)&Wt[(size_t)(kc * 64 + kr) * 768 + N0 + oc];
            else         v = *(const float4*)&Wpa[(size_t)kr * 768 + N0 + oc];
            *(float4*)&Bt[kr][oc] = v;
        }
        __syncthreads();
#pragma unroll 8
        for (int k = 0; k < 64; ++k) {
            float4 a = *(const float4*)&At[k][r0];
            float4 b = *(const float4*)&Bt[k][o0];
            float av[4] = {a.x, a.y, a.z, a.w};
            float bv[4] = {b.x, b.y, b.z, b.w};
#pragma unroll
            for (int i = 0; i < 4; ++i)
#pragma unroll
                for (int j = 0; j < 4; ++j) acc[i * 4 + j] += av[i] * bv[j];
        }
    }
    float4 bias = *(const float4*)&b_attn[N0 + o0];
    float bb[4] = {bias.x, bias.y, bias.z, bias.w};
#pragma unroll
    for (int i = 0; i < 4; ++i) {
        float4 o;
        o.x = acc[i * 4 + 0] + bb[0]; o.y = acc[i * 4 + 1] + bb[1];
        o.z = acc[i * 4 + 2] + bb[2]; o.w = acc[i * 4 + 3] + bb[3];
        *(float4*)&t_attn[(size_t)(M0 + r0 + i) * 768 + N0 + o0] = o;
    }
}

// ---------------- K2 (mega): scores -> softmax -> p, pd (fp32), r GEMM (bf16 MFMA) ----------------
__global__ __launch_bounds__(256) void k_mega(const float* __restrict__ dep,
                                              const int* __restrict__ adj,
                                              const ushort* __restrict__ wdat,
                                              const float* __restrict__ t_attn,
                                              const float* __restrict__ wd_sum,
                                              float* __restrict__ r_out,
                                              float* __restrict__ out_p,
                                              float* __restrict__ pd_out) {
    __shared__ __align__(16) ushort db[128 * 72];  // dep tile bf16, [j][64k + 8 pad]
    __shared__ float wds[64];
    __shared__ float sc[128];
    __shared__ float pv[128];
    __shared__ float pdp[4][64];
    __shared__ float red[8];
    int t = threadIdx.x;
    int bi = blockIdx.x;
    const float* depb = dep + (size_t)bi * (128 * 64);
    // stage dep -> bf16 LDS (A-operand layout: row-major [j][k], +8 pad)
#pragma unroll
    for (int it = 0; it < 8; ++it) {
        int f = t + it * 256;              // float4 index, 0..2047
        int j = f >> 4, k4 = f & 15;
        float4 v = *(const float4*)&depb[(size_t)f * 4];
        union { ushort u[4]; uint2 d; } pk;
        pk.u[0] = f2bf(v.x); pk.u[1] = f2bf(v.y);
        pk.u[2] = f2bf(v.z); pk.u[3] = f2bf(v.w);
        *(uint2*)&db[j * 72 + k4 * 4] = pk.d;
    }
    if (t < 64) wds[t] = wd_sum[t];
    const float* ta = t_attn + (size_t)bi * 768;
    // S_t = sum over o of t_attn row
    float s = ta[t] + ta[t + 256] + ta[t + 512];
#pragma unroll
    for (int off = 32; off; off >>= 1) s += __shfl_down(s, off, 64);
    if ((t & 63) == 0) red[t >> 6] = s;
    __syncthreads();
    float S_t = red[0] + red[1] + red[2] + red[3];
    // scores (fp32, dep from L2-hot global)
    if (t < 128) {
        const float* row = depb + (size_t)t * 64;
        float d = 0.f;
#pragma unroll
        for (int k4 = 0; k4 < 16; ++k4) {
            float4 v = *(const float4*)&row[k4 * 4];
            d += v.x * wds[k4 * 4 + 0] + v.y * wds[k4 * 4 + 1]
               + v.z * wds[k4 * 4 + 2] + v.w * wds[k4 * 4 + 3];
        }
        float sval = S_t + d;
        if (adj[(size_t)bi * 128 + t] == 0) sval += -1e30f;
        sc[t] = sval;
    }
    __syncthreads();
    if (t < 64) {
        float v = fmaxf(sc[t], sc[t + 64]);
#pragma unroll
        for (int off = 32; off; off >>= 1) v = fmaxf(v, __shfl_down(v, off, 64));
        if (t == 0) red[4] = v;
    }
    __syncthreads();
    if (t < 128) pv[t] = __expf(sc[t] - red[4]);
    __syncthreads();
    if (t < 64) {
        float v = pv[t] + pv[t + 64];
#pragma unroll
        for (int off = 32; off; off >>= 1) v += __shfl_down(v, off, 64);
        if (t == 0) red[5] = v;
    }
    __syncthreads();
    float inv = 1.0f / red[5];
    if (t < 128) {
        float pj = pv[t] * inv;
        pv[t] = pj;
        out_p[(size_t)bi * 128 + t] = pj;
    }
    __syncthreads();
    // pd[k] = sum_j p[j] * dep[j][k]  (fp32 from L2-hot global)
    {
        int kk = t & 63, seg = t >> 6;
        float a = 0.f;
#pragma unroll
        for (int jj = 0; jj < 32; ++jj)
            a += pv[seg * 32 + jj] * depb[(size_t)(seg * 32 + jj) * 64 + kk];
        pdp[seg][kk] = a;
    }
    __syncthreads();
    if (t < 64) pd_out[(size_t)bi * 64 + t] = pdp[0][t] + pdp[1][t] + pdp[2][t] + pdp[3][t];

    // ---- r GEMM via bf16 MFMA 16x16x32: r[j][o] = dep[j][:]@Wda[:,o] + ta[o] ----
    int w = t >> 6, l = t & 63;
    int col = l & 15, q = l >> 4;
    // A-fragments: wave w covers j in [w*32, w*32+32), 2 j-tiles, 2 k-halves. Held in regs.
    short8 afr[2][2];
#pragma unroll
    for (int jt = 0; jt < 2; ++jt)
#pragma unroll
        for (int h = 0; h < 2; ++h)
            afr[jt][h] = *(const short8*)&db[(w * 32 + jt * 16 + col) * 72 + h * 32 + q * 8];
    float* rb = r_out + (size_t)bi * (128 * 768);
    for (int oc = 0; oc < 12; ++oc) {
        int O = oc * 64;
        short8 bfr[4][2];
#pragma unroll
        for (int ot = 0; ot < 4; ++ot)
#pragma unroll
            for (int h = 0; h < 2; ++h)
                bfr[ot][h] = *(const short8*)&wdat[(size_t)(O + ot * 16 + col) * 64 + h * 32 + q * 8];
        float tav[4];
#pragma unroll
        for (int ot = 0; ot < 4; ++ot) tav[ot] = ta[O + ot * 16 + col];
#pragma unroll
        for (int ot = 0; ot < 4; ++ot) {
#pragma unroll
            for (int jt = 0; jt < 2; ++jt) {
                v4f acc = {0.f, 0.f, 0.f, 0.f};
                acc = __builtin_amdgcn_mfma_f32_16x16x32_bf16(afr[jt][0], bfr[ot][0], acc, 0, 0, 0);
                acc = __builtin_amdgcn_mfma_f32_16x16x32_bf16(afr[jt][1], bfr[ot][1], acc, 0, 0, 0);
                // D layout: col = lane&15, row = (lane>>4)*4 + reg
                float* dst = rb + (size_t)(w * 32 + jt * 16 + q * 4) * 768 + O + ot * 16 + col;
#pragma unroll
                for (int reg = 0; reg < 4; ++reg)
                    __builtin_nontemporal_store(acc[reg] + tav[ot], dst + (size_t)reg * 768);
            }
        }
    }
}

// ---------------- K3: output_sum = text + pos@Wp + bp + bd + pd@Wd ----------------
__global__ __launch_bounds__(256) void k_out(const float* __restrict__ text,
                                             const float* __restrict__ pos,
                                             const float* __restrict__ Wp,
                                             const float* __restrict__ bp,
                                             const float* __restrict__ Wd,
                                             const float* __restrict__ bd,
                                             const float* __restrict__ pd,
                                             float* __restrict__ outp) {
    __shared__ float ps[8][64];
    __shared__ float pdl[8][64];
    int t = threadIdx.x;
    int bi0 = blockIdx.x * 8;
    for (int f = t; f < 512; f += 256) {
        int g = f >> 6, k = f & 63;
        ps[g][k]  = pos[(size_t)(bi0 + g) * 64 + k];
        pdl[g][k] = pd[(size_t)(bi0 + g) * 64 + k];
    }
    __syncthreads();
    if (t < 192) {
        int d0 = t * 4;
        float acc[32] = {};
#pragma unroll 4
        for (int k = 0; k < 64; ++k) {
            float4 wp = *(const float4*)&Wp[(size_t)k * 768 + d0];
            float4 wd = *(const float4*)&Wd[(size_t)k * 768 + d0];
            float wpv[4] = {wp.x, wp.y, wp.z, wp.w};
            float wdv[4] = {wd.x, wd.y, wd.z, wd.w};
#pragma unroll
            for (int g = 0; g < 8; ++g) {
                float pk = ps[g][k], dk = pdl[g][k];
#pragma unroll
                for (int c = 0; c < 4; ++c) acc[g * 4 + c] += pk * wpv[c] + dk * wdv[c];
            }
        }
        float4 bpv = *(const float4*)&bp[d0];
        float4 bdv = *(const float4*)&bd[d0];
        float bb[4] = {bpv.x + bdv.x, bpv.y + bdv.y, bpv.z + bdv.z, bpv.w + bdv.w};
#pragma unroll
        for (int g = 0; g < 8; ++g) {
            float4 tx = *(const float4*)&text[(size_t)(bi0 + g) * 768 + d0];
            float4 o;
            o.x = acc[g * 4 + 0] + tx.x + bb[0];
            o.y = acc[g * 4 + 1] + tx.y + bb[1];
            o.z = acc[g * 4 + 2] + tx.z + bb[2];
            o.w = acc[g * 4 + 3] + tx.w + bb[3];
            *(float4*)&outp[(size_t)(bi0 + g) * 768 + d0] = o;
        }
    }
}

extern "C" void kernel_launch(void* const* d_in, const int* in_sizes, int n_in,
                              void* d_out, int out_size, void* d_ws, size_t ws_size,
                              hipStream_t stream) {
    const float* text   = (const float*)d_in[0];
    const int*   adj    = (const int*)d_in[1];
    const float* dep    = (const float*)d_in[2];
    const float* pos    = (const float*)d_in[3];
    const float* Wt     = (const float*)d_in[4];
    const float* Wpa    = (const float*)d_in[5];
    const float* Wda    = (const float*)d_in[6];
    const float* b_attn = (const float*)d_in[7];
    const float* Wd     = (const float*)d_in[8];
    const float* bd     = (const float*)d_in[9];
    const float* Wp     = (const float*)d_in[10];
    const float* bp     = (const float*)d_in[11];

    float* out    = (float*)d_out;
    float* r_out  = out;                                   // [8,128,128,768]
    float* os_out = out + (size_t)8 * 128 * 128 * 768;     // [8,128,768]
    float* p_out  = os_out + (size_t)8 * 128 * 768;        // [8,128,128]

    float* ws     = (float*)d_ws;
    float* t_attn = ws;                    // 786432 floats
    float* wd_sum = ws + 786432;           // 64
    float* pd     = ws + 786496;           // 65536
    ushort* wdat  = (ushort*)(ws + 852032);  // 49152 ushorts, 16B-aligned

    k_wdsum<<<64, 256, 0, stream>>>(Wda, wd_sum);
    k_cvt<<<192, 256, 0, stream>>>(Wda, wdat);
    k_tattn<<<dim3(16, 12), 256, 0, stream>>>(text, pos, Wt, Wpa, b_attn, t_attn);
    k_mega<<<1024, 256, 0, stream>>>(dep, adj, wdat, t_attn, wd_sum, r_out, p_out, pd);
    k_out<<<128, 256, 0, stream>>>(text, pos, Wp, bp, Wd, bd, pd, os_out);
}